// Round 2
// baseline (259.743 us; speedup 1.0000x reference)
//
#include <hip/hip_runtime.h>
#include <utility>
#include <cstddef>

#define N_ATOMS 20000
#define N_EDGES 50000
#define FDIM 16
#define NPATHS 33
#define EPB 16   // edges per block

// ======================= compile-time CG table generation =======================
// Reproduces reference _cg / _umat / _real_cg exactly (double precision, cast to float).
namespace cgx {

constexpr double cfac(int n){ double r = 1.0; for (int i = 2; i <= n; ++i) r *= (double)i; return r; }

constexpr double csqrt(double x){
  if (x <= 0.0) return 0.0;
  double g = (x >= 1.0) ? x : 1.0;
  for (int i = 0; i < 200; ++i){
    double ng = 0.5 * (g + x / g);
    if (ng == g) break;
    g = ng;
  }
  return g;
}

constexpr double cg_coef(int j1,int m1,int j2,int m2,int j3,int m3){
  if (m1 + m2 != m3) return 0.0;
  int dlo = (j1 > j2) ? (j1 - j2) : (j2 - j1);
  if (j3 < dlo || j3 > j1 + j2) return 0.0;
  double pre = csqrt((2.0*j3+1.0) * cfac(j3+j1-j2) * cfac(j3-j1+j2) * cfac(j1+j2-j3) / cfac(j1+j2+j3+1));
  pre *= csqrt(cfac(j3+m3)*cfac(j3-m3)*cfac(j1-m1)*cfac(j1+m1)*cfac(j2-m2)*cfac(j2+m2));
  int kmin = 0;
  if (j2 - j3 - m1 > kmin) kmin = j2 - j3 - m1;
  if (j1 - j3 + m2 > kmin) kmin = j1 - j3 + m2;
  int kmax = j1 + j2 - j3;
  if (j1 - m1 < kmax) kmax = j1 - m1;
  if (j2 + m2 < kmax) kmax = j2 + m2;
  double s = 0.0;
  for (int k = kmin; k <= kmax; ++k){
    double t = 1.0 / (cfac(k)*cfac(j1+j2-j3-k)*cfac(j1-m1-k)*cfac(j2+m2-k)*cfac(j3-j2+m1+k)*cfac(j3-j1-m2+k));
    s += (k & 1) ? -t : t;
  }
  return pre * s;
}

struct Cplx { double re; double im; };
constexpr double S2C = 0.70710678118654752440;

constexpr Cplx u_entry(int l, int row, int col){
  int m = row - l;
  if (m > 0){
    if (col == m + l)  return Cplx{ (m & 1) ? -S2C : S2C, 0.0 };
    if (col == -m + l) return Cplx{ S2C, 0.0 };
  } else if (m == 0){
    if (col == l) return Cplx{ 1.0, 0.0 };
  } else {
    int am = -m;
    if (col == m + l)  return Cplx{ 0.0, S2C };
    if (col == am + l) return Cplx{ 0.0, (am & 1) ? S2C : -S2C };  // -i*(-1)^am*s2
  }
  return Cplx{ 0.0, 0.0 };
}

template<int L1,int L2,int L3>
struct CGCTab { double v[(2*L1+1)*(2*L2+1)]; };

template<int L1,int L2,int L3>
constexpr CGCTab<L1,L2,L3> make_cgc(){
  CGCTab<L1,L2,L3> t{};
  for (int A = 0; A < 2*L1+1; ++A){
    for (int B = 0; B < 2*L2+1; ++B){
      int MA = A - L1, MB = B - L2, MC = MA + MB;
      t.v[A*(2*L2+1)+B] = (MC < -L3 || MC > L3) ? 0.0 : cg_coef(L1,MA,L2,MB,L3,MC);
    }
  }
  return t;
}
template<int L1,int L2,int L3>
struct CGCH { static constexpr CGCTab<L1,L2,L3> t = make_cgc<L1,L2,L3>(); };

template<int L1,int L2,int L3>
struct GTab { float v[(2*L1+1)*(2*L2+1)*(2*L3+1)]; };

template<int L1,int L2,int L3>
constexpr GTab<L1,L2,L3> make_g(){
  GTab<L1,L2,L3> g{};
  constexpr int NA = 2*L1+1, NB = 2*L2+1, NC = 2*L3+1;
  for (int a = 0; a < NA; ++a){
    for (int b = 0; b < NB; ++b){
      for (int c = 0; c < NC; ++c){
        double re = 0.0, im = 0.0;
        for (int A = 0; A < NA; ++A){
          Cplx u1 = u_entry(L1, a, A);
          if (u1.re == 0.0 && u1.im == 0.0) continue;
          int MA = A - L1;
          for (int B = 0; B < NB; ++B){
            Cplx u2 = u_entry(L2, b, B);
            if (u2.re == 0.0 && u2.im == 0.0) continue;
            int MB = B - L2;
            int MC = MA + MB;
            if (MC < -L3 || MC > L3) continue;
            Cplx u3 = u_entry(L3, c, MC + L3);
            if (u3.re == 0.0 && u3.im == 0.0) continue;
            double cgv = CGCH<L1,L2,L3>::t.v[A*NB + B];
            if (cgv == 0.0) continue;
            u3.im = -u3.im;  // conj
            double pr = u1.re*u2.re - u1.im*u2.im;
            double pi_ = u1.re*u2.im + u1.im*u2.re;
            re += (pr*u3.re - pi_*u3.im) * cgv;
            im += (pr*u3.im + pi_*u3.re) * cgv;
          }
        }
        g.v[(a*NB + b)*NC + c] = (float)(((L1 + L2 + L3) % 2 == 0) ? re : im);
      }
    }
  }
  return g;
}
template<int L1,int L2,int L3>
struct GH { static constexpr GTab<L1,L2,L3> t = make_g<L1,L2,L3>(); };

struct PathD { int l1, l2, l3; };
constexpr PathD PATHS_C[NPATHS] = {
  {0,0,0},{0,1,1},{0,2,2},{0,3,3},{0,4,4},
  {1,0,1},{1,1,0},{1,1,1},{1,1,2},{1,2,1},{1,2,2},{1,2,3},{1,3,2},{1,3,3},{1,3,4},{1,4,3},{1,4,4},
  {2,0,2},{2,1,1},{2,1,2},{2,1,3},{2,2,0},{2,2,1},{2,2,2},{2,2,3},{2,2,4},
  {2,3,1},{2,3,2},{2,3,3},{2,3,4},{2,4,2},{2,4,3},{2,4,4}
};

constexpr const float* G_PTRS[NPATHS] = {
  GH<0,0,0>::t.v, GH<0,1,1>::t.v, GH<0,2,2>::t.v, GH<0,3,3>::t.v, GH<0,4,4>::t.v,
  GH<1,0,1>::t.v, GH<1,1,0>::t.v, GH<1,1,1>::t.v, GH<1,1,2>::t.v, GH<1,2,1>::t.v,
  GH<1,2,2>::t.v, GH<1,2,3>::t.v, GH<1,3,2>::t.v, GH<1,3,3>::t.v, GH<1,3,4>::t.v,
  GH<1,4,3>::t.v, GH<1,4,4>::t.v,
  GH<2,0,2>::t.v, GH<2,1,1>::t.v, GH<2,1,2>::t.v, GH<2,1,3>::t.v, GH<2,2,0>::t.v,
  GH<2,2,1>::t.v, GH<2,2,2>::t.v, GH<2,2,3>::t.v, GH<2,2,4>::t.v, GH<2,3,1>::t.v,
  GH<2,3,2>::t.v, GH<2,3,3>::t.v, GH<2,3,4>::t.v, GH<2,4,2>::t.v, GH<2,4,3>::t.v,
  GH<2,4,4>::t.v
};

constexpr bool keep(float v){ return v > 1e-12f || v < -1e-12f; }

constexpr int count_nnz_par(int parity){
  int n = 0;
  for (int p = 0; p < NPATHS; ++p){
    int l1 = PATHS_C[p].l1, l2 = PATHS_C[p].l2, l3 = PATHS_C[p].l3;
    if (((l1 + l2 + l3) & 1) != parity) continue;
    int tot = (2*l1+1)*(2*l2+1)*(2*l3+1);
    for (int i = 0; i < tot; ++i) if (keep(G_PTRS[p][i])) ++n;
  }
  return n;
}
constexpr int NNZ0 = count_nnz_par(0);
constexpr int NNZ1 = count_nnz_par(1);
static_assert(NNZ0 > 50 && NNZ1 > 20 && NNZ0 + NNZ1 < 4013, "unexpected CG sparsity");

template<int N>
struct EListN {
  short slot[N];  // l3^2 + c   (local slot within parity half, 0..24)
  short ag[N];    // l1^2 + a   (0..8)
  short bg[N];    // l2^2 + b   (0..24)
  short p[N];     // path index (0..32)
  float val[N];
};

template<int PARITY, int N>
constexpr EListN<N> make_entries_par(){
  EListN<N> E{};
  int n = 0;
  for (int p = 0; p < NPATHS; ++p){
    const int l1 = PATHS_C[p].l1, l2 = PATHS_C[p].l2, l3 = PATHS_C[p].l3;
    if (((l1 + l2 + l3) & 1) != PARITY) continue;
    const int NA = 2*l1+1, NB = 2*l2+1, NC = 2*l3+1;
    for (int a = 0; a < NA; ++a)
      for (int b = 0; b < NB; ++b)
        for (int c = 0; c < NC; ++c){
          const float v = G_PTRS[p][(a*NB + b)*NC + c];
          if (keep(v)){
            E.slot[n] = (short)(l3*l3 + c);
            E.ag[n]   = (short)(l1*l1 + a);
            E.bg[n]   = (short)(l2*l2 + b);
            E.p[n]    = (short)p;
            E.val[n]  = v;
            ++n;
          }
        }
  }
  return E;
}
constexpr EListN<NNZ0> EN0 = make_entries_par<0, NNZ0>();
constexpr EListN<NNZ1> EN1 = make_entries_par<1, NNZ1>();

} // namespace cgx

// ======================= device code =======================

struct Ent { int slot, ag, bg, p; float v; };

template<int PAR>
constexpr Ent get_ent(int i){
  if constexpr (PAR == 0)
    return Ent{ (int)cgx::EN0.slot[i], (int)cgx::EN0.ag[i], (int)cgx::EN0.bg[i], (int)cgx::EN0.p[i], cgx::EN0.val[i] };
  else
    return Ent{ (int)cgx::EN1.slot[i], (int)cgx::EN1.ag[i], (int)cgx::EN1.bg[i], (int)cgx::EN1.p[i], cgx::EN1.val[i] };
}

template<int PAR, int I>
__device__ __forceinline__ void apply_entry(float* __restrict__ acc, const float* __restrict__ sh,
                                            const float* __restrict__ yv, const float* __restrict__ w){
  constexpr Ent e = get_ent<PAR>(I);
  // (w[p]*sh[ag]) CSE'd across entries sharing (p,ag); ((..)*yv[bg]) across (p,ag,bg)
  acc[e.slot] += e.v * ((w[e.p] * sh[e.ag]) * yv[e.bg]);
}

template<int PAR, std::size_t... Is>
__device__ __forceinline__ void apply_all(float* __restrict__ acc, const float* __restrict__ sh,
                                          const float* __restrict__ yv, const float* __restrict__ w,
                                          std::index_sequence<Is...>){
  (apply_entry<PAR, (int)Is>(acc, sh, yv, w), ...);
}

__global__ void __launch_bounds__(512)
BondCenteredTensorMomentDescriptor_62173946576949_kernel(
    const float* __restrict__ desc,   // (N_ATOMS, 1, 25, 16)
    const float* __restrict__ tpw,    // (33, 16)
    const float* __restrict__ disp,   // (E, 3)
    const int*   __restrict__ nidx,   // (E, 2)
    float* __restrict__ out)          // (E, 2, 25, 16)
{
  __shared__ float ylds[EPB * 400];   // summed descriptor pairs, 25.6 KB

  const int e_base = blockIdx.x * EPB;

  // ---- stage y = desc[i0] + desc[i1] into LDS, coalesced float4 ----
  for (int q = threadIdx.x; q < EPB * 100; q += 512){
    const int el = q / 100;           // magic-mul
    const int c  = q - el * 100;      // float4 chunk within row
    const int e  = e_base + el;
    const int i0 = nidx[2*e + 0];
    const int i1 = nidx[2*e + 1];
    const float4 a = *(const float4*)(desc + (size_t)i0 * 400 + c * 4);
    const float4 b = *(const float4*)(desc + (size_t)i1 * 400 + c * 4);
    float4 s; s.x = a.x + b.x; s.y = a.y + b.y; s.z = a.z + b.z; s.w = a.w + b.w;
    *(float4*)(ylds + el * 400 + c * 4) = s;
  }
  __syncthreads();

  // ---- compute: waves 0-3 -> parity 0 slots, waves 4-7 -> parity 1 ----
  const int tt = threadIdx.x & 255;
  const int f  = tt & 15;
  const int el = tt >> 4;
  const int e  = e_base + el;

  const float dx = disp[3*e + 0];
  const float dy = disp[3*e + 1];
  const float dz = disp[3*e + 2];

  const float r   = sqrtf(dx*dx + dy*dy + dz*dz);
  const float inv = 1.0f / fmaxf(r, 1e-9f);
  const float ux = dx*inv, uy = dy*inv, uz = dz*inv;

  float sh[9];
  sh[0] = 0.28209479177387814f;
  sh[1] = 0.4886025119029199f * uy;
  sh[2] = 0.4886025119029199f * uz;
  sh[3] = 0.4886025119029199f * ux;
  sh[4] = 1.0925484305920792f * ux * uy;
  sh[5] = 1.0925484305920792f * uy * uz;
  sh[6] = 0.31539156525252005f * (3.0f * uz * uz - 1.0f);
  sh[7] = 1.0925484305920792f * ux * uz;
  sh[8] = 0.5f * 1.0925484305920792f * (ux*ux - uy*uy);

  // radial sinc(k*r/CUTOFF), k=f+1; rad factors out of ALL entries -> applied at store
  const float px = 3.14159265358979323846f * ((float)(f + 1) * r * 0.2f);
  float rad = (px != 0.0f) ? (__sinf(px) / px) : 1.0f;
  if (!(r < 5.0f)) rad = 0.0f;

  float yv[25];
  #pragma unroll
  for (int b = 0; b < 25; ++b) yv[b] = ylds[el * 400 + b * 16 + f];

  float acc[25];
  #pragma unroll
  for (int i = 0; i < 25; ++i) acc[i] = 0.0f;

  float* __restrict__ op = out + (size_t)e * 800 + f;

  if (threadIdx.x < 256){
    float w[NPATHS];
    #pragma unroll
    for (int p = 0; p < NPATHS; ++p) w[p] = tpw[p * FDIM + f];   // DCE keeps only even paths
    apply_all<0>(acc, sh, yv, w, std::make_index_sequence<cgx::NNZ0>{});
    #pragma unroll
    for (int s = 0; s < 25; ++s) op[s * 16] = acc[s] * rad;
  } else {
    float w[NPATHS];
    #pragma unroll
    for (int p = 0; p < NPATHS; ++p) w[p] = tpw[p * FDIM + f];   // DCE keeps only odd paths
    apply_all<1>(acc, sh, yv, w, std::make_index_sequence<cgx::NNZ1>{});
    // slot 25 (parity1, l3=0) is never produced by any path -> acc[0] stays 0,
    // written as 0 (required: d_out is poisoned 0xAA before every launch)
    #pragma unroll
    for (int s = 0; s < 25; ++s) op[(25 + s) * 16] = acc[s] * rad;
  }
}

extern "C" void kernel_launch(void* const* d_in, const int* in_sizes, int n_in,
                              void* d_out, int out_size, void* d_ws, size_t ws_size,
                              hipStream_t stream) {
  const float* desc = (const float*)d_in[0];
  const float* tpw  = (const float*)d_in[1];
  const float* disp = (const float*)d_in[2];
  const int*   nidx = (const int*)d_in[3];
  float* out = (float*)d_out;

  const int grid = N_EDGES / EPB;   // 3125, exact
  BondCenteredTensorMomentDescriptor_62173946576949_kernel<<<grid, 512, 0, stream>>>(
      desc, tpw, disp, nidx, out);
}

// Round 3
// 206.219 us; speedup vs baseline: 1.2595x; 1.2595x over previous
//
#include <hip/hip_runtime.h>
#include <utility>
#include <cstddef>

#define N_ATOMS 20000
#define N_EDGES 50000
#define FDIM 16
#define NPATHS 33
#define EPB 16   // edges per block (256 threads = 16 edges x 16 f)

// ======================= compile-time CG table generation =======================
// Reproduces reference _cg / _umat / _real_cg exactly (double precision, cast to float).
namespace cgx {

constexpr double cfac(int n){ double r = 1.0; for (int i = 2; i <= n; ++i) r *= (double)i; return r; }

constexpr double csqrt(double x){
  if (x <= 0.0) return 0.0;
  double g = (x >= 1.0) ? x : 1.0;
  for (int i = 0; i < 200; ++i){
    double ng = 0.5 * (g + x / g);
    if (ng == g) break;
    g = ng;
  }
  return g;
}

constexpr double cg_coef(int j1,int m1,int j2,int m2,int j3,int m3){
  if (m1 + m2 != m3) return 0.0;
  int dlo = (j1 > j2) ? (j1 - j2) : (j2 - j1);
  if (j3 < dlo || j3 > j1 + j2) return 0.0;
  double pre = csqrt((2.0*j3+1.0) * cfac(j3+j1-j2) * cfac(j3-j1+j2) * cfac(j1+j2-j3) / cfac(j1+j2+j3+1));
  pre *= csqrt(cfac(j3+m3)*cfac(j3-m3)*cfac(j1-m1)*cfac(j1+m1)*cfac(j2-m2)*cfac(j2+m2));
  int kmin = 0;
  if (j2 - j3 - m1 > kmin) kmin = j2 - j3 - m1;
  if (j1 - j3 + m2 > kmin) kmin = j1 - j3 + m2;
  int kmax = j1 + j2 - j3;
  if (j1 - m1 < kmax) kmax = j1 - m1;
  if (j2 + m2 < kmax) kmax = j2 + m2;
  double s = 0.0;
  for (int k = kmin; k <= kmax; ++k){
    double t = 1.0 / (cfac(k)*cfac(j1+j2-j3-k)*cfac(j1-m1-k)*cfac(j2+m2-k)*cfac(j3-j2+m1+k)*cfac(j3-j1-m2+k));
    s += (k & 1) ? -t : t;
  }
  return pre * s;
}

struct Cplx { double re; double im; };
constexpr double S2C = 0.70710678118654752440;

constexpr Cplx u_entry(int l, int row, int col){
  int m = row - l;
  if (m > 0){
    if (col == m + l)  return Cplx{ (m & 1) ? -S2C : S2C, 0.0 };
    if (col == -m + l) return Cplx{ S2C, 0.0 };
  } else if (m == 0){
    if (col == l) return Cplx{ 1.0, 0.0 };
  } else {
    int am = -m;
    if (col == m + l)  return Cplx{ 0.0, S2C };
    if (col == am + l) return Cplx{ 0.0, (am & 1) ? S2C : -S2C };  // -i*(-1)^am*s2
  }
  return Cplx{ 0.0, 0.0 };
}

template<int L1,int L2,int L3>
struct CGCTab { double v[(2*L1+1)*(2*L2+1)]; };

template<int L1,int L2,int L3>
constexpr CGCTab<L1,L2,L3> make_cgc(){
  CGCTab<L1,L2,L3> t{};
  for (int A = 0; A < 2*L1+1; ++A){
    for (int B = 0; B < 2*L2+1; ++B){
      int MA = A - L1, MB = B - L2, MC = MA + MB;
      t.v[A*(2*L2+1)+B] = (MC < -L3 || MC > L3) ? 0.0 : cg_coef(L1,MA,L2,MB,L3,MC);
    }
  }
  return t;
}
template<int L1,int L2,int L3>
struct CGCH { static constexpr CGCTab<L1,L2,L3> t = make_cgc<L1,L2,L3>(); };

template<int L1,int L2,int L3>
struct GTab { float v[(2*L1+1)*(2*L2+1)*(2*L3+1)]; };

template<int L1,int L2,int L3>
constexpr GTab<L1,L2,L3> make_g(){
  GTab<L1,L2,L3> g{};
  constexpr int NA = 2*L1+1, NB = 2*L2+1, NC = 2*L3+1;
  for (int a = 0; a < NA; ++a){
    for (int b = 0; b < NB; ++b){
      for (int c = 0; c < NC; ++c){
        double re = 0.0, im = 0.0;
        for (int A = 0; A < NA; ++A){
          Cplx u1 = u_entry(L1, a, A);
          if (u1.re == 0.0 && u1.im == 0.0) continue;
          int MA = A - L1;
          for (int B = 0; B < NB; ++B){
            Cplx u2 = u_entry(L2, b, B);
            if (u2.re == 0.0 && u2.im == 0.0) continue;
            int MB = B - L2;
            int MC = MA + MB;
            if (MC < -L3 || MC > L3) continue;
            Cplx u3 = u_entry(L3, c, MC + L3);
            if (u3.re == 0.0 && u3.im == 0.0) continue;
            double cgv = CGCH<L1,L2,L3>::t.v[A*NB + B];
            if (cgv == 0.0) continue;
            u3.im = -u3.im;  // conj
            double pr = u1.re*u2.re - u1.im*u2.im;
            double pi_ = u1.re*u2.im + u1.im*u2.re;
            re += (pr*u3.re - pi_*u3.im) * cgv;
            im += (pr*u3.im + pi_*u3.re) * cgv;
          }
        }
        g.v[(a*NB + b)*NC + c] = (float)(((L1 + L2 + L3) % 2 == 0) ? re : im);
      }
    }
  }
  return g;
}
template<int L1,int L2,int L3>
struct GH { static constexpr GTab<L1,L2,L3> t = make_g<L1,L2,L3>(); };

struct PathD { int l1, l2, l3; };
constexpr PathD PATHS_C[NPATHS] = {
  {0,0,0},{0,1,1},{0,2,2},{0,3,3},{0,4,4},
  {1,0,1},{1,1,0},{1,1,1},{1,1,2},{1,2,1},{1,2,2},{1,2,3},{1,3,2},{1,3,3},{1,3,4},{1,4,3},{1,4,4},
  {2,0,2},{2,1,1},{2,1,2},{2,1,3},{2,2,0},{2,2,1},{2,2,2},{2,2,3},{2,2,4},
  {2,3,1},{2,3,2},{2,3,3},{2,3,4},{2,4,2},{2,4,3},{2,4,4}
};

constexpr const float* G_PTRS[NPATHS] = {
  GH<0,0,0>::t.v, GH<0,1,1>::t.v, GH<0,2,2>::t.v, GH<0,3,3>::t.v, GH<0,4,4>::t.v,
  GH<1,0,1>::t.v, GH<1,1,0>::t.v, GH<1,1,1>::t.v, GH<1,1,2>::t.v, GH<1,2,1>::t.v,
  GH<1,2,2>::t.v, GH<1,2,3>::t.v, GH<1,3,2>::t.v, GH<1,3,3>::t.v, GH<1,3,4>::t.v,
  GH<1,4,3>::t.v, GH<1,4,4>::t.v,
  GH<2,0,2>::t.v, GH<2,1,1>::t.v, GH<2,1,2>::t.v, GH<2,1,3>::t.v, GH<2,2,0>::t.v,
  GH<2,2,1>::t.v, GH<2,2,2>::t.v, GH<2,2,3>::t.v, GH<2,2,4>::t.v, GH<2,3,1>::t.v,
  GH<2,3,2>::t.v, GH<2,3,3>::t.v, GH<2,3,4>::t.v, GH<2,4,2>::t.v, GH<2,4,3>::t.v,
  GH<2,4,4>::t.v
};

constexpr bool keep(float v){ return v > 1e-12f || v < -1e-12f; }

constexpr int count_nnz(){
  int n = 0;
  for (int p = 0; p < NPATHS; ++p){
    int l1 = PATHS_C[p].l1, l2 = PATHS_C[p].l2, l3 = PATHS_C[p].l3;
    int tot = (2*l1+1)*(2*l2+1)*(2*l3+1);
    for (int i = 0; i < tot; ++i) if (keep(G_PTRS[p][i])) ++n;
  }
  return n;
}
constexpr int NNZ = count_nnz();
static_assert(NNZ > 100 && NNZ < 4013, "unexpected CG sparsity");

struct EntryList {
  short c[NNZ];   // local output component within path (0..2*l3)
  short ag[NNZ];  // l1^2 + a (0..8)
  short bg[NNZ];  // l2^2 + b (0..24)
  float val[NNZ];
};

constexpr EntryList make_entries(){   // path-major order
  EntryList E{};
  int n = 0;
  for (int p = 0; p < NPATHS; ++p){
    const int l1 = PATHS_C[p].l1, l2 = PATHS_C[p].l2, l3 = PATHS_C[p].l3;
    const int NA = 2*l1+1, NB = 2*l2+1, NC = 2*l3+1;
    for (int a = 0; a < NA; ++a)
      for (int b = 0; b < NB; ++b)
        for (int c = 0; c < NC; ++c){
          const float v = G_PTRS[p][(a*NB + b)*NC + c];
          if (keep(v)){
            E.c[n]  = (short)c;
            E.ag[n] = (short)(l1*l1 + a);
            E.bg[n] = (short)(l2*l2 + b);
            E.val[n]= v;
            ++n;
          }
        }
  }
  return E;
}
constexpr EntryList EN = make_entries();

struct POff { int v[NPATHS + 1]; };
constexpr POff make_poff(){
  POff o{};
  int n = 0;
  o.v[0] = 0;
  for (int p = 0; p < NPATHS; ++p){
    const int l1 = PATHS_C[p].l1, l2 = PATHS_C[p].l2, l3 = PATHS_C[p].l3;
    const int NA = 2*l1+1, NB = 2*l2+1, NC = 2*l3+1;
    for (int a = 0; a < NA; ++a)
      for (int b = 0; b < NB; ++b)
        for (int c = 0; c < NC; ++c)
          if (keep(G_PTRS[p][(a*NB + b)*NC + c])) ++n;
    o.v[p + 1] = n;
  }
  return o;
}
constexpr POff POFF = make_poff();

// pacc first-touch: is entry I the first in path P to write component c?
constexpr bool pacc_first(int P, int I){
  for (int j = POFF.v[P]; j < I; ++j) if (EN.c[j] == EN.c[I]) return false;
  return true;
}
// does path P produce component C at all?
constexpr bool touched(int P, int C){
  for (int j = POFF.v[P]; j < POFF.v[P + 1]; ++j) if (EN.c[j] == C) return true;
  return false;
}
constexpr int path_base(int p){
  const int l1 = PATHS_C[p].l1, l2 = PATHS_C[p].l2, l3 = PATHS_C[p].l3;
  return ((l1 + l2 + l3) & 1) * 25 + l3 * l3;
}
// acc first-touch: is path P the first path to write global slot path_base(P)+C?
constexpr bool slot_first(int P, int C){
  const int s = path_base(P) + C;
  for (int q = 0; q < P; ++q){
    const int b = path_base(q), nc = 2 * PATHS_C[q].l3 + 1;
    if (s >= b && s < b + nc && touched(q, s - b)) return false;
  }
  return true;
}
// is slot s (0..49) ever written by any path?
constexpr bool slot_used(int s){
  for (int q = 0; q < NPATHS; ++q){
    const int b = path_base(q), nc = 2 * PATHS_C[q].l3 + 1;
    if (s >= b && s < b + nc && touched(q, s - b)) return true;
  }
  return false;
}

} // namespace cgx

// ======================= device code =======================

template<int P, int I>
__device__ __forceinline__ void entry_op(float* __restrict__ pacc, const float* __restrict__ sh,
                                         const float* __restrict__ yv){
  constexpr int   c  = cgx::EN.c[I];
  constexpr int   ag = cgx::EN.ag[I];
  constexpr int   bg = cgx::EN.bg[I];
  constexpr float v  = cgx::EN.val[I];
  const float t = sh[ag] * yv[bg];          // CSE'd across entries/paths sharing (ag,bg)
  if constexpr (cgx::pacc_first(P, I)) pacc[c] = v * t;
  else                                 pacc[c] += v * t;   // v_fmac with literal src0
}

template<int P, std::size_t... Is>
__device__ __forceinline__ void path_entries(float* __restrict__ pacc, const float* __restrict__ sh,
                                             const float* __restrict__ yv, std::index_sequence<Is...>){
  (entry_op<P, cgx::POFF.v[P] + (int)Is>(pacc, sh, yv), ...);
}

template<int P, int C>
__device__ __forceinline__ void path_out_one(float* __restrict__ acc, const float* __restrict__ pacc, float wp){
  if constexpr (cgx::touched(P, C)){
    constexpr int s = cgx::path_base(P) + C;
    if constexpr (cgx::slot_first(P, C)) acc[s] = wp * pacc[C];
    else                                 acc[s] += wp * pacc[C];
  }
}

template<int P, std::size_t... Cs>
__device__ __forceinline__ void path_out(float* __restrict__ acc, const float* __restrict__ pacc, float wp,
                                         std::index_sequence<Cs...>){
  (path_out_one<P, (int)Cs>(acc, pacc, wp), ...);
}

template<int P>
__device__ __forceinline__ void apply_path(float* __restrict__ acc, const float* __restrict__ sh,
                                           const float* __restrict__ yv, const float* __restrict__ tplds,
                                           int f){
  constexpr int NC = 2 * cgx::PATHS_C[P].l3 + 1;
  float pacc[NC];
  path_entries<P>(pacc, sh, yv, std::make_index_sequence<(std::size_t)(cgx::POFF.v[P+1] - cgx::POFF.v[P])>{});
  const float wp = tplds[P * FDIM + f];     // ds_read_b32, immediate offset
  path_out<P>(acc, pacc, wp, std::make_index_sequence<NC>{});
}

template<std::size_t... Ps>
__device__ __forceinline__ void apply_paths(float* __restrict__ acc, const float* __restrict__ sh,
                                            const float* __restrict__ yv, const float* __restrict__ tplds,
                                            int f, std::index_sequence<Ps...>){
  (apply_path<(int)Ps>(acc, sh, yv, tplds, f), ...);
}

template<int S>
__device__ __forceinline__ void store_slot(float* __restrict__ op, const float* __restrict__ acc){
  if constexpr (cgx::slot_used(S)) op[S * FDIM] = acc[S];
  else                             op[S * FDIM] = 0.0f;   // e.g. parity-1 l3=0 slot
}
template<std::size_t... Ss>
__device__ __forceinline__ void store_all(float* __restrict__ op, const float* __restrict__ acc,
                                          std::index_sequence<Ss...>){
  (store_slot<(int)Ss>(op, acc), ...);
}

__global__ void __launch_bounds__(256)
BondCenteredTensorMomentDescriptor_62173946576949_kernel(
    const float* __restrict__ desc,   // (N_ATOMS, 1, 25, 16)
    const float* __restrict__ tpw,    // (33, 16)
    const float* __restrict__ disp,   // (E, 3)
    const int*   __restrict__ nidx,   // (E, 2)
    float* __restrict__ out)          // (E, 2, 25, 16)
{
  __shared__ float ylds[EPB * 400];          // 25.6 KB: summed descriptor pairs
  __shared__ float tplds[NPATHS * FDIM];     // 2.1 KB: tp_weights

  const int e_base = blockIdx.x * EPB;
  const int tid = threadIdx.x;
  const int f  = tid & 15;
  const int el = tid >> 4;                   // 0..15, this thread's edge row
  const int e  = e_base + el;

  // ---- stage y = desc[i0]+desc[i1] into LDS (division-free, float4 coalesced) ----
  {
    const int i0 = nidx[2*e + 0];
    const int i1 = nidx[2*e + 1];
    const float* __restrict__ a0 = desc + (size_t)i0 * 400;
    const float* __restrict__ a1 = desc + (size_t)i1 * 400;
    #pragma unroll
    for (int k = 0; k < 7; ++k){
      const int c = f + 16 * k;              // float4 chunk 0..99
      if (c < 100){
        const float4 A = *(const float4*)(a0 + c * 4);
        const float4 B = *(const float4*)(a1 + c * 4);
        float4 s; s.x = A.x + B.x; s.y = A.y + B.y; s.z = A.z + B.z; s.w = A.w + B.w;
        *(float4*)(ylds + el * 400 + c * 4) = s;
      }
    }
  }
  for (int q = tid; q < NPATHS * FDIM; q += 256) tplds[q] = tpw[q];
  __syncthreads();

  // ---- per-(edge,f) geometry ----
  const float dx = disp[3*e + 0];
  const float dy = disp[3*e + 1];
  const float dz = disp[3*e + 2];
  const float r   = sqrtf(dx*dx + dy*dy + dz*dz);
  const float inv = 1.0f / fmaxf(r, 1e-9f);
  const float ux = dx*inv, uy = dy*inv, uz = dz*inv;

  // radial sinc(k*r/CUTOFF), k=f+1; rad is a common factor of every term ->
  // folded into sh[] (each entry has exactly one sh factor)
  const float px = 3.14159265358979323846f * ((float)(f + 1) * r * 0.2f);
  float rad = (px != 0.0f) ? (__sinf(px) / px) : 1.0f;
  if (!(r < 5.0f)) rad = 0.0f;

  float sh[9];
  sh[0] = 0.28209479177387814f * rad;
  sh[1] = (0.4886025119029199f * rad) * uy;
  sh[2] = (0.4886025119029199f * rad) * uz;
  sh[3] = (0.4886025119029199f * rad) * ux;
  {
    const float c2r = 1.0925484305920792f * rad;
    sh[4] = c2r * ux * uy;
    sh[5] = c2r * uy * uz;
    sh[6] = (0.31539156525252005f * rad) * (3.0f * uz * uz - 1.0f);
    sh[7] = c2r * ux * uz;
    sh[8] = 0.5f * c2r * (ux*ux - uy*uy);
  }

  float yv[25];
  #pragma unroll
  for (int b = 0; b < 25; ++b) yv[b] = ylds[el * 400 + b * 16 + f];

  float acc[50];   // first-touch assigned per slot at compile time; unused slots never read
  apply_paths(acc, sh, yv, tplds, f, std::make_index_sequence<NPATHS>{});

  float* __restrict__ op = out + (size_t)e * 800 + f;
  store_all(op, acc, std::make_index_sequence<50>{});
}

extern "C" void kernel_launch(void* const* d_in, const int* in_sizes, int n_in,
                              void* d_out, int out_size, void* d_ws, size_t ws_size,
                              hipStream_t stream) {
  const float* desc = (const float*)d_in[0];
  const float* tpw  = (const float*)d_in[1];
  const float* disp = (const float*)d_in[2];
  const int*   nidx = (const int*)d_in[3];
  float* out = (float*)d_out;

  const int grid = N_EDGES / EPB;   // 3125, exact
  BondCenteredTensorMomentDescriptor_62173946576949_kernel<<<grid, 256, 0, stream>>>(
      desc, tpw, disp, nidx, out);
}